// Round 9
// baseline (557.371 us; speedup 1.0000x reference)
//
#include <hip/hip_runtime.h>
#include <hip/hip_bf16.h>

// LSTM: B=16384, T=200, IN=9, H=64, OUT=3, 2 layers + linear head.
// Round 9: dual-tile blocks. Block = 32 batches = 2 independent 16-batch
//   tiles (P,Q) sharing the same register-resident weights (112 VGPR reused).
//   One barrier serves both tiles' h-exchange -> barrier/idle amortized over
//   2x work; grid 512 blocks = fully resident in ONE round (was 2 rounds).
//   Tile Q's MFMA cluster overlaps tile P's transcendental cell chain.
//   + s_setprio(1) around post-barrier compute (phase-diverse blocks).
// 256 threads (4 waves). Wave w owns gate n-tiles {w, w+4, w+8, w+12}.
// Fragment layouts (gfx950 16x16x32, verified R2-R8):
//   A: lane l holds A[m=l&15][k=4*(l>>4)+(j&3)+16*(j>>2)]
//   B: lane l holds B[k=...][n=l&15]
//   C/D: col=l&15, row=(l>>4)*4+reg
// LDS h-state k-PERMUTED (R3). Weight pre-scale (R7): i,f,o x(-log2e), g x(-2log2e).
// cell math (R8): merged-reciprocal + batched 4-way rcp.

#define B_TOT   16384
#define T_STEPS 200
#define IN_DIM  9
#define HDIM    64

#define PK1_OFF 0         // [3][16][64][8] = 24576 f16
#define PK2_OFF 24576     // [4][16][64][8] = 32768 f16
#define BSUM_HALF_OFF 57344   // then 512 f32 (b1[256], b2[256])
#define PACK_W_TOT 57344
#define PACK_TOT (PACK_W_TOT + 512)

#define L2E     1.44269504089f
#define TWOL2E  2.88539008178f

typedef _Float16 half8  __attribute__((ext_vector_type(8)));
typedef _Float16 half4v __attribute__((ext_vector_type(4)));
typedef float    f32x4  __attribute__((ext_vector_type(4)));
typedef float    f4u    __attribute__((ext_vector_type(4), aligned(4)));

// ---------------- prep: repack weights (B-frag layout, scales folded) -------
__global__ void pack_kernel(const float* __restrict__ Wih1, const float* __restrict__ Whh1,
                            const float* __restrict__ bih1, const float* __restrict__ bhh1,
                            const float* __restrict__ Wih2, const float* __restrict__ Whh2,
                            const float* __restrict__ bih2, const float* __restrict__ bhh2,
                            float* __restrict__ ws) {
    int e = blockIdx.x * 256 + threadIdx.x;
    if (e >= PACK_TOT) return;
    _Float16* wh = (_Float16*)ws;
    float* bptr = (float*)(wh + BSUM_HALF_OFF);
    auto gscale = [](int q) -> float {
        int gt = q >> 6;                       // 0=i,1=f,2=g,3=o
        return (gt == 2) ? (-2.0f * L2E) : -L2E;
    };
    if (e < PK2_OFF) {
        int j = e & 7, lane = (e >> 3) & 63, nt = (e >> 9) & 15, c = e >> 13;
        int k = c * 32 + 4 * (lane >> 4) + (j & 3) + 16 * (j >> 2);
        int q = nt * 16 + (lane & 15);
        float v = 0.0f;
        if (k < 64)      v = Whh1[q * 64 + k];
        else if (k < 73) v = Wih1[q * 9 + (k - 64)];
        wh[e] = (_Float16)(v * gscale(q));
    } else if (e < PACK_W_TOT) {
        int e2 = e - PK2_OFF;
        int j = e2 & 7, lane = (e2 >> 3) & 63, nt = (e2 >> 9) & 15, c = e2 >> 13;
        int k = c * 32 + 4 * (lane >> 4) + (j & 3) + 16 * (j >> 2);
        int q = nt * 16 + (lane & 15);
        float v = (k < 64) ? Wih2[q * 64 + k] : Whh2[q * 64 + (k - 64)];
        wh[e] = (_Float16)(v * gscale(q));
    } else if (e < PACK_W_TOT + 256) {
        int q = e - PACK_W_TOT;
        bptr[q] = (bih1[q] + bhh1[q]) * gscale(q);
    } else {
        int q = e - PACK_W_TOT - 256;
        bptr[256 + q] = (bih2[q] + bhh2[q]) * gscale(q);
    }
}

// ---------------- main sequential LSTM ----------------
__global__ __launch_bounds__(256, 2) void lstm_mfma(
    const float* __restrict__ x,
    const float* __restrict__ ws_f,
    const float* __restrict__ Wout,
    const float* __restrict__ bout,
    float* __restrict__ out)
{
    const int tid  = threadIdx.x;
    const int lane = tid & 63;
    const int w    = __builtin_amdgcn_readfirstlane(tid >> 6);   // 0..3
    const int l15  = lane & 15;
    const int l4   = lane >> 4;

    const _Float16* wh  = (const _Float16*)ws_f;
    const _Float16* pk1 = wh + PK1_OFF;
    const _Float16* pk2 = wh + PK2_OFF;
    const float* bsum   = (const float*)(wh + BSUM_HALF_OFF);

    // per-tile state: h double-buffered, x windows
    __shared__ _Float16 h1P[2][16][72], h2P[2][16][72];
    __shared__ _Float16 h1Q[2][16][72], h2Q[2][16][72];
    __shared__ _Float16 xwP[2][8][4][16][4], xwQ[2][8][4][16][4];

    for (int i = tid; i < 2 * 16 * 72; i += 256) {
        (&h1P[0][0][0])[i] = (_Float16)0.0f; (&h2P[0][0][0])[i] = (_Float16)0.0f;
        (&h1Q[0][0][0])[i] = (_Float16)0.0f; (&h2Q[0][0][0])[i] = (_Float16)0.0f;
    }
    for (int i = tid; i < 2 * 8 * 4 * 16 * 4; i += 256) {
        (&xwP[0][0][0][0][0])[i] = (_Float16)0.0f;
        (&xwQ[0][0][0][0][0])[i] = (_Float16)0.0f;
    }

    const int bbase = blockIdx.x * 32;

    // ---- x loaders (R8 scheme, one per tile): thread = batch b_, slots pz
    const int b_ = tid & 15, z_ = tid >> 4;
    const int s0_ = (z_ * 11) >> 5, q0_ = z_ - 3 * s0_;
    const bool act1 = (z_ < 8);
    const int pz1 = z_ + 16;
    const int s1_ = (pz1 * 11) >> 5, q1_ = pz1 - 3 * s1_;
    const float* xbP = x + (long)(bbase + b_) * (T_STEPS * IN_DIM);
    const float* xbQ = x + (long)(bbase + 16 + b_) * (T_STEPS * IN_DIM);

    f4u pfPA = {0.f,0.f,0.f,0.f}, pfPB = {0.f,0.f,0.f,0.f};
    f4u pfQA = {0.f,0.f,0.f,0.f}, pfQB = {0.f,0.f,0.f,0.f};

    auto fetch_t = [&](const float* xb, f4u& A, f4u& B, int wb) {
        int t0 = wb + s0_; if (t0 > T_STEPS - 1) t0 = T_STEPS - 1;
        const float* p0 = xb + t0 * IN_DIM + 4 * q0_;
        if (q0_ < 2) A = *(const f4u*)p0; else A[0] = p0[0];
        if (act1) {
            int t1 = wb + s1_; if (t1 > T_STEPS - 1) t1 = T_STEPS - 1;
            const float* p1 = xb + t1 * IN_DIM + 4 * q1_;
            if (q1_ < 2) B = *(const f4u*)p1; else B[0] = p1[0];
        }
    };
    auto store_t = [&](_Float16 (*xw)[8][4][16][4], f4u A, f4u B, int buf) {
        if (q0_ == 2) { A[1] = 0.f; A[2] = 0.f; A[3] = 0.f; }
        half4v hv;
        hv[0] = (_Float16)A[0]; hv[1] = (_Float16)A[1];
        hv[2] = (_Float16)A[2]; hv[3] = (_Float16)A[3];
        *(half4v*)&xw[buf][s0_][q0_][b_][0] = hv;
        if (act1) {
            if (q1_ == 2) { B[1] = 0.f; B[2] = 0.f; B[3] = 0.f; }
            half4v hw;
            hw[0] = (_Float16)B[0]; hw[1] = (_Float16)B[1];
            hw[2] = (_Float16)B[2]; hw[3] = (_Float16)B[3];
            *(half4v*)&xw[buf][s1_][q1_][b_][0] = hw;
        }
    };
    auto read_ax = [&](const _Float16 (*xw)[8][4][16][4], int tt) -> half8 {
        half4v xq = *(const half4v*)&xw[(tt >> 3) & 1][tt & 7][l4][l15][0];
        return __builtin_shufflevector(xq, xq, 0, 1, 2, 3, 0, 1, 2, 3);
    };

    // ---- weight B-fragments: 28 x half8, loop-pinned, SHARED by both tiles
    half8 bw1_00, bw1_01, bw1_02, bw1_03;
    half8 bw1_10, bw1_11, bw1_12, bw1_13;
    half8 bw1_20, bw1_21, bw1_22, bw1_23;
    half8 bw2_00, bw2_01, bw2_02, bw2_03;
    half8 bw2_10, bw2_11, bw2_12, bw2_13;
    half8 bw2_20, bw2_21, bw2_22, bw2_23;
    half8 bw2_30, bw2_31, bw2_32, bw2_33;
    {
        #define LD1(c,g) *(const half8*)(pk1 + (((c * 16) + (w + 4 * g)) * 64 + lane) * 8)
        #define LD2(c,g) *(const half8*)(pk2 + (((c * 16) + (w + 4 * g)) * 64 + lane) * 8)
        bw1_00 = LD1(0,0); bw1_01 = LD1(0,1); bw1_02 = LD1(0,2); bw1_03 = LD1(0,3);
        bw1_10 = LD1(1,0); bw1_11 = LD1(1,1); bw1_12 = LD1(1,2); bw1_13 = LD1(1,3);
        bw1_20 = LD1(2,0); bw1_21 = LD1(2,1); bw1_22 = LD1(2,2); bw1_23 = LD1(2,3);
        bw2_00 = LD2(0,0); bw2_01 = LD2(0,1); bw2_02 = LD2(0,2); bw2_03 = LD2(0,3);
        bw2_10 = LD2(1,0); bw2_11 = LD2(1,1); bw2_12 = LD2(1,2); bw2_13 = LD2(1,3);
        bw2_20 = LD2(2,0); bw2_21 = LD2(2,1); bw2_22 = LD2(2,2); bw2_23 = LD2(2,3);
        bw2_30 = LD2(3,0); bw2_31 = LD2(3,1); bw2_32 = LD2(3,2); bw2_33 = LD2(3,3);
        #undef LD1
        #undef LD2
    }

    float bias1[4], bias2[4];
    #pragma unroll
    for (int g = 0; g < 4; ++g) {
        bias1[g] = bsum[(w + 4 * g) * 16 + l15];
        bias2[g] = bsum[256 + (w + 4 * g) * 16 + l15];
    }

    const int hpos = ((w >> 1) << 5) + 8 * (l15 >> 2) + (l15 & 3) + ((w & 1) << 2);

    f32x4 c1P = {0.f,0.f,0.f,0.f}, c2P = {0.f,0.f,0.f,0.f};
    f32x4 c1Q = {0.f,0.f,0.f,0.f}, c2Q = {0.f,0.f,0.f,0.f};

    // merged cell update (R8): batched 4-way reciprocals
    auto cell_update = [&](f32x4* G, f32x4& cs, _Float16* hb) {
        float num[4], den[4], eo4[4], d2[4], hs4[4];
        #pragma unroll
        for (int r = 0; r < 4; ++r) {
            float ei = __builtin_amdgcn_exp2f(G[0][r]);
            float ef = __builtin_amdgcn_exp2f(G[1][r]);
            float eg = __builtin_amdgcn_exp2f(G[2][r]);
            eo4[r]   = __builtin_amdgcn_exp2f(G[3][r]);
            float ai = 1.0f + ei, af = 1.0f + ef, ag = 1.0f + eg;
            float gm = 1.0f - eg;
            float pp = ai * ag;
            num[r] = __builtin_fmaf(gm, af, cs[r] * pp);
            den[r] = af * pp;
        }
        float s01 = den[0] * den[1], s23 = den[2] * den[3];
        float Pinv = __builtin_amdgcn_rcpf(s01 * s23);
        float r01 = Pinv * s23, r23 = Pinv * s01;
        float inv[4] = {r01 * den[1], r01 * den[0], r23 * den[3], r23 * den[2]};
        #pragma unroll
        for (int r = 0; r < 4; ++r) {
            float cc = num[r] * inv[r];
            cs[r] = cc;
            float z  = cc * TWOL2E;
            int   zi = __float_as_int(z);
            float ec = __builtin_amdgcn_exp2f(__int_as_float(zi | (int)0x80000000));
            float tm = 1.0f - ec;
            d2[r] = (1.0f + eo4[r]) * (1.0f + ec);
            hs4[r] = __int_as_float(__float_as_int(tm) ^ (zi & (int)0x80000000));
        }
        float t01 = d2[0] * d2[1], t23 = d2[2] * d2[3];
        float Qinv = __builtin_amdgcn_rcpf(t01 * t23);
        float q01 = Qinv * t23, q23 = Qinv * t01;
        float jnv[4] = {q01 * d2[1], q01 * d2[0], q23 * d2[3], q23 * d2[2]};
        #pragma unroll
        for (int r = 0; r < 4; ++r)
            hb[(4 * l4 + r) * 72 + hpos] = (_Float16)(hs4[r] * jnv[r]);
    };

    // MFMA clusters (weights captured by ref)
    auto initb = [&](f32x4* A, const float* b) {
        #pragma unroll
        for (int g = 0; g < 4; ++g) A[g] = (f32x4){b[g], b[g], b[g], b[g]};
    };
    auto L2C = [&](f32x4* D, half8 u0, half8 u1, half8 v0, half8 v1) {
        D[0] = __builtin_amdgcn_mfma_f32_16x16x32_f16(u0, bw2_00, D[0], 0, 0, 0);
        D[1] = __builtin_amdgcn_mfma_f32_16x16x32_f16(u0, bw2_01, D[1], 0, 0, 0);
        D[2] = __builtin_amdgcn_mfma_f32_16x16x32_f16(u0, bw2_02, D[2], 0, 0, 0);
        D[3] = __builtin_amdgcn_mfma_f32_16x16x32_f16(u0, bw2_03, D[3], 0, 0, 0);
        D[0] = __builtin_amdgcn_mfma_f32_16x16x32_f16(u1, bw2_10, D[0], 0, 0, 0);
        D[1] = __builtin_amdgcn_mfma_f32_16x16x32_f16(u1, bw2_11, D[1], 0, 0, 0);
        D[2] = __builtin_amdgcn_mfma_f32_16x16x32_f16(u1, bw2_12, D[2], 0, 0, 0);
        D[3] = __builtin_amdgcn_mfma_f32_16x16x32_f16(u1, bw2_13, D[3], 0, 0, 0);
        D[0] = __builtin_amdgcn_mfma_f32_16x16x32_f16(v0, bw2_20, D[0], 0, 0, 0);
        D[1] = __builtin_amdgcn_mfma_f32_16x16x32_f16(v0, bw2_21, D[1], 0, 0, 0);
        D[2] = __builtin_amdgcn_mfma_f32_16x16x32_f16(v0, bw2_22, D[2], 0, 0, 0);
        D[3] = __builtin_amdgcn_mfma_f32_16x16x32_f16(v0, bw2_23, D[3], 0, 0, 0);
        D[0] = __builtin_amdgcn_mfma_f32_16x16x32_f16(v1, bw2_30, D[0], 0, 0, 0);
        D[1] = __builtin_amdgcn_mfma_f32_16x16x32_f16(v1, bw2_31, D[1], 0, 0, 0);
        D[2] = __builtin_amdgcn_mfma_f32_16x16x32_f16(v1, bw2_32, D[2], 0, 0, 0);
        D[3] = __builtin_amdgcn_mfma_f32_16x16x32_f16(v1, bw2_33, D[3], 0, 0, 0);
    };
    auto L1C = [&](f32x4* C, half8 u0, half8 u1, half8 axm) {
        C[0] = __builtin_amdgcn_mfma_f32_16x16x32_f16(u0, bw1_00, C[0], 0, 0, 0);
        C[1] = __builtin_amdgcn_mfma_f32_16x16x32_f16(u0, bw1_01, C[1], 0, 0, 0);
        C[2] = __builtin_amdgcn_mfma_f32_16x16x32_f16(u0, bw1_02, C[2], 0, 0, 0);
        C[3] = __builtin_amdgcn_mfma_f32_16x16x32_f16(u0, bw1_03, C[3], 0, 0, 0);
        C[0] = __builtin_amdgcn_mfma_f32_16x16x32_f16(u1, bw1_10, C[0], 0, 0, 0);
        C[1] = __builtin_amdgcn_mfma_f32_16x16x32_f16(u1, bw1_11, C[1], 0, 0, 0);
        C[2] = __builtin_amdgcn_mfma_f32_16x16x32_f16(u1, bw1_12, C[2], 0, 0, 0);
        C[3] = __builtin_amdgcn_mfma_f32_16x16x32_f16(u1, bw1_13, C[3], 0, 0, 0);
        C[0] = __builtin_amdgcn_mfma_f32_16x16x32_f16(axm, bw1_20, C[0], 0, 0, 0);
        C[1] = __builtin_amdgcn_mfma_f32_16x16x32_f16(axm, bw1_21, C[1], 0, 0, 0);
        C[2] = __builtin_amdgcn_mfma_f32_16x16x32_f16(axm, bw1_22, C[2], 0, 0, 0);
        C[3] = __builtin_amdgcn_mfma_f32_16x16x32_f16(axm, bw1_23, C[3], 0, 0, 0);
    };

    #define PIN_ALL() do {                                                      \
        asm volatile("" :                                                       \
            "+v"(bw1_00), "+v"(bw1_01), "+v"(bw1_02), "+v"(bw1_03),             \
            "+v"(bw1_10), "+v"(bw1_11), "+v"(bw1_12), "+v"(bw1_13),             \
            "+v"(bw1_20), "+v"(bw1_21), "+v"(bw1_22), "+v"(bw1_23));            \
        asm volatile("" :                                                       \
            "+v"(bw2_00), "+v"(bw2_01), "+v"(bw2_02), "+v"(bw2_03),             \
            "+v"(bw2_10), "+v"(bw2_11), "+v"(bw2_12), "+v"(bw2_13),             \
            "+v"(bw2_20), "+v"(bw2_21), "+v"(bw2_22), "+v"(bw2_23),             \
            "+v"(bw2_30), "+v"(bw2_31), "+v"(bw2_32), "+v"(bw2_33),             \
            "+v"(bias1[0]), "+v"(bias1[1]), "+v"(bias1[2]), "+v"(bias1[3]),     \
            "+v"(bias2[0]), "+v"(bias2[1]), "+v"(bias2[2]), "+v"(bias2[3]));    \
    } while (0)

    // ---- preloop: windows + C init for both tiles
    fetch_t(xbP, pfPA, pfPB, 0);
    fetch_t(xbQ, pfQA, pfQB, 0);
    __syncthreads();                        // LDS zeros committed
    store_t(xwP, pfPA, pfPB, 0);
    store_t(xwQ, pfQA, pfQB, 0);
    fetch_t(xbP, pfPA, pfPB, 8);
    fetch_t(xbQ, pfQA, pfQB, 8);
    __syncthreads();                        // window 0 + zero h visible

    f32x4 CP[4], CQ[4];
    {
        half8 ax0 = read_ax(xwP, 0);
        initb(CP, bias1);
        CP[0] = __builtin_amdgcn_mfma_f32_16x16x32_f16(ax0, bw1_20, CP[0], 0, 0, 0);
        CP[1] = __builtin_amdgcn_mfma_f32_16x16x32_f16(ax0, bw1_21, CP[1], 0, 0, 0);
        CP[2] = __builtin_amdgcn_mfma_f32_16x16x32_f16(ax0, bw1_22, CP[2], 0, 0, 0);
        CP[3] = __builtin_amdgcn_mfma_f32_16x16x32_f16(ax0, bw1_23, CP[3], 0, 0, 0);
        half8 ax1 = read_ax(xwQ, 0);
        initb(CQ, bias1);
        CQ[0] = __builtin_amdgcn_mfma_f32_16x16x32_f16(ax1, bw1_20, CQ[0], 0, 0, 0);
        CQ[1] = __builtin_amdgcn_mfma_f32_16x16x32_f16(ax1, bw1_21, CQ[1], 0, 0, 0);
        CQ[2] = __builtin_amdgcn_mfma_f32_16x16x32_f16(ax1, bw1_22, CQ[2], 0, 0, 0);
        CQ[3] = __builtin_amdgcn_mfma_f32_16x16x32_f16(ax1, bw1_23, CQ[3], 0, 0, 0);
    }

    for (int t = 0; t < T_STEPS; t += 2) {
        // ============ body A (step t): writes parity 1, reads h2 parity 0
        PIN_ALL();
        cell_update(CP, c1P, &h1P[1][0][0]);
        cell_update(CQ, c1Q, &h1Q[1][0][0]);
        if ((t & 7) == 0) {
            int nb = ((t >> 3) + 1) & 1;
            store_t(xwP, pfPA, pfPB, nb);
            store_t(xwQ, pfQA, pfQB, nb);
            fetch_t(xbP, pfPA, pfPB, t + 16);
            fetch_t(xbQ, pfQA, pfQB, t + 16);
        }
        __syncthreads();                    // h1(t) both tiles visible
        __builtin_amdgcn_s_setprio(1);
        {   // tile P
            half8 u0 = *(const half8*)&h1P[1][l15][ 0 + 8 * l4];
            half8 u1 = *(const half8*)&h1P[1][l15][32 + 8 * l4];
            half8 v0 = *(const half8*)&h2P[0][l15][ 0 + 8 * l4];
            half8 v1 = *(const half8*)&h2P[0][l15][32 + 8 * l4];
            half8 axm = read_ax(xwP, t + 1);
            f32x4 D[4]; initb(D, bias2);
            L2C(D, u0, u1, v0, v1);
            initb(CP, bias1);               // CP reborn as gates1(t+1)
            L1C(CP, u0, u1, axm);
            cell_update(D, c2P, &h2P[1][0][0]);
        }
        {   // tile Q (independent of P's trans chain -> overlaps)
            half8 u0 = *(const half8*)&h1Q[1][l15][ 0 + 8 * l4];
            half8 u1 = *(const half8*)&h1Q[1][l15][32 + 8 * l4];
            half8 v0 = *(const half8*)&h2Q[0][l15][ 0 + 8 * l4];
            half8 v1 = *(const half8*)&h2Q[0][l15][32 + 8 * l4];
            half8 axm = read_ax(xwQ, t + 1);
            f32x4 D[4]; initb(D, bias2);
            L2C(D, u0, u1, v0, v1);
            initb(CQ, bias1);
            L1C(CQ, u0, u1, axm);
            cell_update(D, c2Q, &h2Q[1][0][0]);
        }
        __builtin_amdgcn_s_setprio(0);

        // ============ body B (step t+1): writes parity 0, reads h2 parity 1
        PIN_ALL();
        cell_update(CP, c1P, &h1P[0][0][0]);
        cell_update(CQ, c1Q, &h1Q[0][0][0]);
        __syncthreads();                    // h1(t+1) visible
        __builtin_amdgcn_s_setprio(1);
        {   // tile P
            half8 u0 = *(const half8*)&h1P[0][l15][ 0 + 8 * l4];
            half8 u1 = *(const half8*)&h1P[0][l15][32 + 8 * l4];
            half8 v0 = *(const half8*)&h2P[1][l15][ 0 + 8 * l4];
            half8 v1 = *(const half8*)&h2P[1][l15][32 + 8 * l4];
            half8 axm = read_ax(xwP, t + 2);
            f32x4 D[4]; initb(D, bias2);
            L2C(D, u0, u1, v0, v1);
            initb(CP, bias1);
            L1C(CP, u0, u1, axm);
            cell_update(D, c2P, &h2P[0][0][0]);
        }
        {   // tile Q
            half8 u0 = *(const half8*)&h1Q[0][l15][ 0 + 8 * l4];
            half8 u1 = *(const half8*)&h1Q[0][l15][32 + 8 * l4];
            half8 v0 = *(const half8*)&h2Q[1][l15][ 0 + 8 * l4];
            half8 v1 = *(const half8*)&h2Q[1][l15][32 + 8 * l4];
            half8 axm = read_ax(xwQ, t + 2);
            f32x4 D[4]; initb(D, bias2);
            L2C(D, u0, u1, v0, v1);
            initb(CQ, bias1);
            L1C(CQ, u0, u1, axm);
            cell_update(D, c2Q, &h2Q[0][0][0]);
        }
        __builtin_amdgcn_s_setprio(0);
    }
    __syncthreads();   // final h2 writes visible

    // ---- output head: 32 batches x 3 outs = 96 threads; h2(199) in parity 0
    if (tid < 96) {
        int bl = tid / 3, o = tid - bl * 3;
        const _Float16* src = (bl < 16) ? &h2P[0][bl][0] : &h2Q[0][bl - 16][0];
        float acc = bout[o];
        #pragma unroll 8
        for (int pos = 0; pos < HDIM; ++pos) {
            int sub = pos & 31;
            int j = (pos >> 5) * 32 + (((sub >> 2) & 1) << 4) + ((sub >> 3) << 2) + (sub & 3);
            acc = __builtin_fmaf(Wout[o * 64 + j], (float)src[pos], acc);
        }
        out[(bbase + bl) * 3 + o] = acc;
    }
    #undef PIN_ALL
}

extern "C" void kernel_launch(void* const* d_in, const int* in_sizes, int n_in,
                              void* d_out, int out_size, void* d_ws, size_t ws_size,
                              hipStream_t stream) {
    const float* x     = (const float*)d_in[0];
    const float* Wih1  = (const float*)d_in[1];
    const float* Whh1  = (const float*)d_in[2];
    const float* bih1  = (const float*)d_in[3];
    const float* bhh1  = (const float*)d_in[4];
    const float* Wih2  = (const float*)d_in[5];
    const float* Whh2  = (const float*)d_in[6];
    const float* bih2  = (const float*)d_in[7];
    const float* bhh2  = (const float*)d_in[8];
    const float* Wout  = (const float*)d_in[9];
    const float* bout  = (const float*)d_in[10];
    float* ws  = (float*)d_ws;
    float* out = (float*)d_out;

    pack_kernel<<<(PACK_TOT + 255) / 256, 256, 0, stream>>>(
        Wih1, Whh1, bih1, bhh1, Wih2, Whh2, bih2, bhh2, ws);

    lstm_mfma<<<B_TOT / 32, 256, 0, stream>>>(x, ws, Wout, bout, out);
}